// Round 19
// baseline (211.846 us; speedup 1.0000x reference)
//
#include <hip/hip_runtime.h>
#include <math.h>

#define A_TOT 8400
#define B_N   2
#define T_N   100
#define C_N   80
#define E_N   32
#define MH_N  64
#define MW_N  64
#define ROW_N 8363          // 4 + 80 + 85 + 4096 + 4098
#define NROWS (B_N*A_TOT)   // 16800
#define EPSF  1e-9f
#define COMP_CAP 1536       // positives per bt bounded by 1189 (grid mask)
#define NEGINF -1e30f
#define SCORE_B  200
#define TRANS_E  216        // blocks [200,216): transpose t_masks
#define PREP_B   280        // blocks [216,280): small fields 0..83
#define GOUT  2100          // x4 waves = 8400 waves = 2 rows/wave

typedef float vfloat4 __attribute__((ext_vector_type(4)));

__device__ __forceinline__ float2 tmat_eval(
    float gx1, float gy1, float gx2, float gy2,
    float ax,  float ay,
    float px1, float py1, float px2, float py2,
    float cl, float atg, float atp) {
  float ix1 = fmaxf(gx1,px1), iy1 = fmaxf(gy1,py1);
  float ix2 = fminf(gx2,px2), iy2 = fminf(gy2,py2);
  float inter = fmaxf(ix2-ix1,0.f) * fmaxf(iy2-iy1,0.f);
  float wg = gx2-gx1, hg = gy2-gy1, wp = px2-px1, hp = py2-py1;
  float uni = wg*hg + wp*hp - inter + EPSF;
  float iou = inter / uni;
  float cw = fmaxf(gx2,px2) - fminf(gx1,px1);
  float ch = fmaxf(gy2,py2) - fminf(gy1,py1);
  float c2 = cw*cw + ch*ch + EPSF;
  float dx = gx1+gx2-px1-px2, dy = gy1+gy2-py1-py2;
  float rho2 = (dx*dx + dy*dy) * 0.25f;
  float da = atg - atp;
  float v  = 0.4052847345693511f * da * da;     // 4/pi^2
  float alpha = v / (1.f - iou + v + EPSF);
  float ciou = iou - rho2/c2 - alpha*v;
  float iouc = fminf(fmaxf(ciou, 0.f), 1.f);

  float tm = 0.f;
  if (ax > gx1 && ay > gy1 && ax < gx2 && ay < gy2) {   // strict grid mask
    float cp = 1.f / (1.f + expf(-cl));
    float i2 = iouc * iouc;
    tm = i2*i2*i2 * sqrtf(cp);                 // iou^6 * cls^0.5
  }
  return make_float2(tm, iouc);
}

// ---- node 2: score (blocks 0..199) + t_masks transpose (200..215)
//              + assignment-independent small fields (216..279) -------------
__global__ __launch_bounds__(512) void k_prep(
    const float* __restrict__ cls_logits, const float* __restrict__ pred_boxes,
    const float* __restrict__ target_bbox, const int* __restrict__ target_cls,
    const float* __restrict__ anchors, const float* __restrict__ scalers,
    const float* __restrict__ t_masks,
    float* __restrict__ tmatT, float* __restrict__ tmaskT,
    float* __restrict__ kth, float* __restrict__ maxt, float* __restrict__ maxiou,
    float* __restrict__ out) {
  int tid  = threadIdx.x;
  int lane = tid & 63, wid = tid >> 6;
  unsigned bx = blockIdx.x;
  __shared__ float comp[COMP_CAP];
  __shared__ float redm[8], redi[8];
  __shared__ float wtop[8][10];
  __shared__ int   cnt;

  if (bx >= PREP_B) return;
  if (bx >= TRANS_E) {
    // ---- small fields 0..83 for every row (wave-per-row) ----
    unsigned wg = (bx - TRANS_E)*8u + (unsigned)wid;        // 0..511
    for (unsigned row = wg; row < (unsigned)NROWS; row += 512u) {
      int a = (int)(row >= (unsigned)A_TOT ? row - A_TOT : row);
      float s = scalers[a];
      size_t base = (size_t)row * ROW_N;
      {
        unsigned p = (unsigned)lane;             // 0..63
        float val = (p < 4u) ? pred_boxes[(size_t)row*4 + p] / s
                             : cls_logits[(size_t)row*C_N + (p-4u)];
        out[base + p] = val;
      }
      if (lane < 20) {
        unsigned p = 64u + (unsigned)lane;       // 64..83
        out[base + p] = cls_logits[(size_t)row*C_N + (p-4u)];
      }
    }
    return;
  }
  if (bx >= SCORE_B) {
    // ---- transpose t_masks [b][h][w][t] -> tmaskT [b][t][h][w] ----
    int g = ((int)bx - SCORE_B)*512 + tid;               // 0..8191
    for (int task = g; task < B_N*T_N*MH_N; task += (TRANS_E-SCORE_B)*512) {
      int b = task / (T_N*MH_N);
      int r = task - b*T_N*MH_N;
      int t = r / MH_N, h = r - t*MH_N;
      const float* src = t_masks + ((size_t)((b*MH_N + h)*MW_N))*T_N + t;
      float* dst = tmaskT + ((size_t)((b*T_N + t)*MH_N + h))*MW_N;
      #pragma unroll 4
      for (int w = 0; w < MW_N; w++) dst[w] = src[(size_t)w*T_N];
    }
    return;
  }

  // ---- score one bt (verbatim round-17 k_score) ----
  int bt = (int)bx, b = bt / T_N, t = bt - b*T_N;
  if (tid == 0) cnt = 0;
  __syncthreads();

  float4 g  = *(const float4*)(target_bbox + bt*4);
  int    tc = target_cls[bt];
  float atg = atanf((g.z - g.x) / ((g.w - g.y) + EPSF));

  float lm = 0.f, li = 0.f;
  for (int a = tid; a < A_TOT; a += 512) {
    float ax = anchors[a*2+0], ay = anchors[a*2+1];
    float4 pb = *(const float4*)(pred_boxes + ((size_t)(b*A_TOT+a))*4);
    float cl = cls_logits[((size_t)(b*A_TOT+a))*C_N + tc];
    float atp = atanf((pb.z - pb.x) / ((pb.w - pb.y) + EPSF));
    float2 r = tmat_eval(g.x,g.y,g.z,g.w, ax,ay, pb.x,pb.y,pb.z,pb.w,
                         cl, atg, atp);
    tmatT[((size_t)b*A_TOT + a)*T_N + t] = r.x;
    li = fmaxf(li, r.y);
    if (r.x > 0.f) {
      lm = fmaxf(lm, r.x);
      comp[atomicAdd(&cnt, 1)] = r.x;
    }
  }
  #pragma unroll
  for (int off = 32; off; off >>= 1) {
    lm = fmaxf(lm, __shfl_xor(lm, off));
    li = fmaxf(li, __shfl_xor(li, off));
  }
  if (lane == 0) { redm[wid] = lm; redi[wid] = li; }
  __syncthreads();
  if (tid == 0) {
    float m = redm[0], mi = redi[0];
    #pragma unroll
    for (int w = 1; w < 8; w++) { m = fmaxf(m, redm[w]); mi = fmaxf(mi, redi[w]); }
    maxt[bt] = m; maxiou[bt] = mi;
  }
  int count = cnt;   // safe: after __syncthreads

  int base = wid*64 + lane;
  float e0 = (base        < count) ? comp[base]        : NEGINF;
  float e1 = (base + 512  < count) ? comp[base + 512]  : NEGINF;
  float e2 = (base + 1024 < count) ? comp[base + 1024] : NEGINF;
  float mytop = NEGINF;
  #pragma unroll
  for (int k = 0; k < 10; k++) {
    float bv = e0; int bs = 0;
    if (e1 > bv) { bv = e1; bs = 1; }
    if (e2 > bv) { bv = e2; bs = 2; }
    float v = bv; int id = (lane << 2) | bs;
    #pragma unroll
    for (int off = 32; off; off >>= 1) {
      float ov = __shfl_xor(v, off); int oid = __shfl_xor(id, off);
      if (ov > v || (ov == v && oid < id)) { v = ov; id = oid; }
    }
    if ((id >> 2) == lane) {
      int s = id & 3;
      if (s == 0) e0 = NEGINF; else if (s == 1) e1 = NEGINF; else e2 = NEGINF;
    }
    if (lane == k) mytop = v;
  }
  if (lane < 10) wtop[wid][lane] = mytop;
  __syncthreads();

  if (wid == 0) {
    int ia = lane, ib = 64 + lane;
    float f0 = wtop[ia/10][ia%10];
    float f1 = (ib < 80) ? wtop[ib/10][ib%10] : NEGINF;
    float cur = NEGINF;
    #pragma unroll
    for (int k = 0; k < 10; k++) {
      float bv = f0; int bs = 0;
      if (f1 > bv) { bv = f1; bs = 1; }
      float v = bv; int id = (lane << 1) | bs;
      #pragma unroll
      for (int off = 32; off; off >>= 1) {
        float ov = __shfl_xor(v, off); int oid = __shfl_xor(id, off);
        if (ov > v || (ov == v && oid < id)) { v = ov; id = oid; }
      }
      if ((id >> 1) == lane) { if ((id & 1) == 0) f0 = NEGINF; else f1 = NEGINF; }
      cur = v;
    }
    if (lane == 0) kth[bt] = fmaxf(cur, 0.f);   // <10 positives -> 0 (ref zero-pad)
  }
}

// ---- node 3: LEAN wave-per-row assign + sparse write ----------------------
__global__ __launch_bounds__(256) void k_out(
    const float* __restrict__ mask_embs,  const float* __restrict__ protos,
    const float* __restrict__ tmaskT,     const float* __restrict__ tmatT,
    const float* __restrict__ kth, const float* __restrict__ maxt,
    const float* __restrict__ maxiou, const float* __restrict__ target_bbox,
    const int* __restrict__ target_cls, const float* __restrict__ scalers,
    float* __restrict__ out) {
  int lane = threadIdx.x & 63;
  int wid  = threadIdx.x >> 6;
  __shared__ float semb_s[4][E_N];              // per-wave slice: no barrier needed
  unsigned wg = blockIdx.x * 4u + (unsigned)wid;

  for (unsigned row = wg; row < (unsigned)NROWS; row += GOUT*4u) {
    int b = row >= (unsigned)A_TOT;
    int a = (int)row - b*A_TOT;

    // assignment: lane l holds candidates t=l and t=l+64
    const float* trow = tmatT + (size_t)row * T_N;
    float v1 = 0.f; int t1 = 0x7fff;
    {
      float va = (lane < T_N) ? trow[lane] : 0.f;
      if (lane < T_N && va > 0.f && va >= kth[b*T_N + lane]) { v1 = va; t1 = lane; }
      int l2 = lane + 64;
      if (l2 < T_N) {
        float vb = trow[l2];
        if (vb > 0.f && vb >= kth[b*T_N + l2]) {
          if (vb > v1) { v1 = vb; t1 = l2; }   // tie keeps smaller t
        }
      }
    }
    #pragma unroll
    for (int off = 32; off; off >>= 1) {
      float ov = __shfl_xor(v1, off); int ot = __shfl_xor(t1, off);
      if (ov > v1 || (ov == v1 && ot < t1)) { v1 = ov; t1 = ot; }
    }
    int  anyv = v1 > 0.f;
    int  u    = anyv ? t1 : 0;
    int  bu   = b*T_N + u;
    float4 tb = *(const float4*)(target_bbox + bu*4);
    float ng  = anyv ? v1 / (maxt[bu] + EPSF) * maxiou[bu] : 0.f;
    float vld = anyv ? 1.f : 0.f;
    float s   = scalers[a];
    float area = (tb.z - tb.x)*(tb.w - tb.y)/(640.f*640.f);
    int  ct   = target_cls[bu];
    bool valid = anyv != 0;
    size_t base = (size_t)row * ROW_N;

    if (lane < E_N) semb_s[wid][lane] = mask_embs[(size_t)row*E_N + lane];

    // assignment-dependent small fields only (8 lanes)
    if (lane < 8) {
      if (lane < 4) {
        float t = (lane==0)?tb.x:((lane==1)?tb.y:((lane==2)?tb.z:tb.w));
        out[base + 84 + lane] = t / s;
      }
      else if (lane == 4) out[base + 88] = vld;
      else if (lane == 5) { if (valid) out[base + 89 + ct] = ng; }
      else if (lane == 6) out[base + 4265] = area;
      else                out[base + 4266] = vld;
    }

    if (valid) {
      float x1s=tb.x*0.1f, y1s=tb.y*0.1f, x2s=tb.z*0.1f, y2s=tb.w*0.1f;
      int hlo = max(0, (int)ceilf(y1s)), hhi = min(MH_N, (int)ceilf(y2s));
      int wlo = max(0, (int)ceilf(x1s)), whi = min(MW_N, (int)ceilf(x2s));
      int nw = whi - wlo, nh = hhi - hlo;
      int ncell = (nw > 0 && nh > 0) ? nw * nh : 0;
      const float* tmrow = tmaskT + (size_t)(b*T_N + u) * (MH_N*MW_N);
      for (int i = lane; i < ncell; i += 64) {
        int h = hlo + i / nw, w = wlo + i % nw;
        const float* pr = protos + ((size_t)((b*MH_N + h)*MW_N + w)) * E_N;
        float acc = 0.f;
        #pragma unroll
        for (int e = 0; e < E_N; e++) acc += semb_s[wid][e] * pr[e];
        int p = (h << 6) | w;
        out[base + 169  + p] = 1.f / (1.f + expf(-acc));
        out[base + 4267 + p] = tmrow[p];
      }
    }
  }
}

extern "C" void kernel_launch(void* const* d_in, const int* in_sizes, int n_in,
                              void* d_out, int out_size, void* d_ws, size_t ws_size,
                              hipStream_t stream) {
  const float* cls_logits   = (const float*)d_in[0];
  const float* pred_boxes   = (const float*)d_in[1];
  const float* mask_embs    = (const float*)d_in[2];
  const float* protos       = (const float*)d_in[3];
  const int*   target_cls   = (const int*)  d_in[4];
  const float* target_bbox  = (const float*)d_in[5];
  const float* target_masks = (const float*)d_in[6];
  const float* anchors      = (const float*)d_in[7];
  const float* scalers      = (const float*)d_in[8];
  float* out = (float*)d_out;

  // ws layout (floats); ~10 MB total
  float* ws     = (float*)d_ws;
  float* tmatT  = ws;                                  // 1,680,000  [row][t]
  float* tmaskT = tmatT + (size_t)NROWS*T_N;           // 819,200    [b][t][h][w]
  float* kth    = tmaskT + (size_t)B_N*T_N*MH_N*MW_N;  // 200
  float* maxt   = kth + B_N*T_N;                       // 200
  float* maxiou = maxt + B_N*T_N;                      // 200

  hipMemsetAsync(out, 0, (size_t)out_size * sizeof(float), stream);
  k_prep<<<PREP_B, 512, 0, stream>>>(cls_logits, pred_boxes, target_bbox,
                                     target_cls, anchors, scalers, target_masks,
                                     tmatT, tmaskT, kth, maxt, maxiou, out);
  k_out<<<GOUT, 256, 0, stream>>>(mask_embs, protos, tmaskT, tmatT,
                                  kth, maxt, maxiou, target_bbox,
                                  target_cls, scalers, out);
}

// Round 20
// 173.797 us; speedup vs baseline: 1.2189x; 1.2189x over previous
//
#include <hip/hip_runtime.h>
#include <math.h>

#define A_TOT 8400
#define B_N   2
#define T_N   100
#define C_N   80
#define E_N   32
#define MH_N  64
#define MW_N  64
#define ROW_N 8363          // 4 + 80 + 85 + 4096 + 4098
#define NROWS (B_N*A_TOT)   // 16800
#define EPSF  1e-9f
#define COMP_CAP 1536       // positives per bt bounded by 1189 (grid mask)
#define NEGINF -1e30f
#define SCORE_B  200
#define PREP_B   456        // blocks [200,456): transpose t_masks (coalesced reads)
#define GOUT  4200          // x4 waves = 16800 waves = 1 row/wave

typedef float vfloat4 __attribute__((ext_vector_type(4)));

__device__ __forceinline__ float2 tmat_eval(
    float gx1, float gy1, float gx2, float gy2,
    float ax,  float ay,
    float px1, float py1, float px2, float py2,
    float cl, float atg, float atp) {
  float ix1 = fmaxf(gx1,px1), iy1 = fmaxf(gy1,py1);
  float ix2 = fminf(gx2,px2), iy2 = fminf(gy2,py2);
  float inter = fmaxf(ix2-ix1,0.f) * fmaxf(iy2-iy1,0.f);
  float wg = gx2-gx1, hg = gy2-gy1, wp = px2-px1, hp = py2-py1;
  float uni = wg*hg + wp*hp - inter + EPSF;
  float iou = inter / uni;
  float cw = fmaxf(gx2,px2) - fminf(gx1,px1);
  float ch = fmaxf(gy2,py2) - fminf(gy1,py1);
  float c2 = cw*cw + ch*ch + EPSF;
  float dx = gx1+gx2-px1-px2, dy = gy1+gy2-py1-py2;
  float rho2 = (dx*dx + dy*dy) * 0.25f;
  float da = atg - atp;
  float v  = 0.4052847345693511f * da * da;     // 4/pi^2
  float alpha = v / (1.f - iou + v + EPSF);
  float ciou = iou - rho2/c2 - alpha*v;
  float iouc = fminf(fmaxf(ciou, 0.f), 1.f);

  float tm = 0.f;
  if (ax > gx1 && ay > gy1 && ax < gx2 && ay < gy2) {   // strict grid mask
    float cp = 1.f / (1.f + expf(-cl));
    float i2 = iouc * iouc;
    tm = i2*i2*i2 * sqrtf(cp);                 // iou^6 * cls^0.5
  }
  return make_float2(tm, iouc);
}

// ---- node 2: score (blocks 0..199) + t_masks transpose (200..455) ---------
__global__ __launch_bounds__(512) void k_prep(
    const float* __restrict__ cls_logits, const float* __restrict__ pred_boxes,
    const float* __restrict__ target_bbox, const int* __restrict__ target_cls,
    const float* __restrict__ anchors, const float* __restrict__ t_masks,
    float* __restrict__ tmatT, float* __restrict__ tmaskT,
    float* __restrict__ kth, float* __restrict__ maxt, float* __restrict__ maxiou) {
  int tid  = threadIdx.x;
  int lane = tid & 63, wid = tid >> 6;
  unsigned bx = blockIdx.x;
  __shared__ float comp[COMP_CAP];
  __shared__ float redm[8], redi[8];
  __shared__ float wtop[8][10];
  __shared__ int   cnt;

  if (bx >= SCORE_B) {
    // ---- transpose t_masks [b][h][w][t] -> tmaskT [b][t][h][w] ----
    // src is read LINEARLY (fully coalesced); dst scatter absorbed by L2.
    const int NTH = (PREP_B - SCORE_B) * 512;          // 131072
    int g = ((int)bx - SCORE_B)*512 + tid;
    const int TOT = B_N*T_N*MH_N*MW_N;                 // 819200
    for (int i = g; i < TOT; i += NTH) {
      float v = t_masks[i];                            // [b][h][w][t] linear
      int t = i % T_N;
      int r = i / T_N;
      int w = r & 63, r2 = r >> 6;
      int h = r2 & 63, b = r2 >> 6;
      tmaskT[((size_t)((b*T_N + t)*MH_N + h))*MW_N + w] = v;
    }
    return;
  }

  // ---- score one bt (verbatim round-17 k_score) ----
  int bt = (int)bx, b = bt / T_N, t = bt - b*T_N;
  if (tid == 0) cnt = 0;
  __syncthreads();

  float4 g  = *(const float4*)(target_bbox + bt*4);
  int    tc = target_cls[bt];
  float atg = atanf((g.z - g.x) / ((g.w - g.y) + EPSF));

  float lm = 0.f, li = 0.f;
  for (int a = tid; a < A_TOT; a += 512) {
    float ax = anchors[a*2+0], ay = anchors[a*2+1];
    float4 pb = *(const float4*)(pred_boxes + ((size_t)(b*A_TOT+a))*4);
    float cl = cls_logits[((size_t)(b*A_TOT+a))*C_N + tc];
    float atp = atanf((pb.z - pb.x) / ((pb.w - pb.y) + EPSF));
    float2 r = tmat_eval(g.x,g.y,g.z,g.w, ax,ay, pb.x,pb.y,pb.z,pb.w,
                         cl, atg, atp);
    tmatT[((size_t)b*A_TOT + a)*T_N + t] = r.x;
    li = fmaxf(li, r.y);
    if (r.x > 0.f) {
      lm = fmaxf(lm, r.x);
      comp[atomicAdd(&cnt, 1)] = r.x;
    }
  }
  #pragma unroll
  for (int off = 32; off; off >>= 1) {
    lm = fmaxf(lm, __shfl_xor(lm, off));
    li = fmaxf(li, __shfl_xor(li, off));
  }
  if (lane == 0) { redm[wid] = lm; redi[wid] = li; }
  __syncthreads();
  if (tid == 0) {
    float m = redm[0], mi = redi[0];
    #pragma unroll
    for (int w = 1; w < 8; w++) { m = fmaxf(m, redm[w]); mi = fmaxf(mi, redi[w]); }
    maxt[bt] = m; maxiou[bt] = mi;
  }
  int count = cnt;   // safe: after __syncthreads

  int base = wid*64 + lane;
  float e0 = (base        < count) ? comp[base]        : NEGINF;
  float e1 = (base + 512  < count) ? comp[base + 512]  : NEGINF;
  float e2 = (base + 1024 < count) ? comp[base + 1024] : NEGINF;
  float mytop = NEGINF;
  #pragma unroll
  for (int k = 0; k < 10; k++) {
    float bv = e0; int bs = 0;
    if (e1 > bv) { bv = e1; bs = 1; }
    if (e2 > bv) { bv = e2; bs = 2; }
    float v = bv; int id = (lane << 2) | bs;
    #pragma unroll
    for (int off = 32; off; off >>= 1) {
      float ov = __shfl_xor(v, off); int oid = __shfl_xor(id, off);
      if (ov > v || (ov == v && oid < id)) { v = ov; id = oid; }
    }
    if ((id >> 2) == lane) {
      int s = id & 3;
      if (s == 0) e0 = NEGINF; else if (s == 1) e1 = NEGINF; else e2 = NEGINF;
    }
    if (lane == k) mytop = v;
  }
  if (lane < 10) wtop[wid][lane] = mytop;
  __syncthreads();

  if (wid == 0) {
    int ia = lane, ib = 64 + lane;
    float f0 = wtop[ia/10][ia%10];
    float f1 = (ib < 80) ? wtop[ib/10][ib%10] : NEGINF;
    float cur = NEGINF;
    #pragma unroll
    for (int k = 0; k < 10; k++) {
      float bv = f0; int bs = 0;
      if (f1 > bv) { bv = f1; bs = 1; }
      float v = bv; int id = (lane << 1) | bs;
      #pragma unroll
      for (int off = 32; off; off >>= 1) {
        float ov = __shfl_xor(v, off); int oid = __shfl_xor(id, off);
        if (ov > v || (ov == v && oid < id)) { v = ov; id = oid; }
      }
      if ((id >> 1) == lane) { if ((id & 1) == 0) f0 = NEGINF; else f1 = NEGINF; }
      cur = v;
    }
    if (lane == 0) kth[bt] = fmaxf(cur, 0.f);   // <10 positives -> 0 (ref zero-pad)
  }
}

// ---- node 3: wave-per-row assign + sparse write (R17 + coalesced tmaskT) --
__global__ __launch_bounds__(256) void k_out(
    const float* __restrict__ cls_logits, const float* __restrict__ pred_boxes,
    const float* __restrict__ mask_embs,  const float* __restrict__ protos,
    const float* __restrict__ tmaskT,     const float* __restrict__ tmatT,
    const float* __restrict__ kth, const float* __restrict__ maxt,
    const float* __restrict__ maxiou, const float* __restrict__ target_bbox,
    const int* __restrict__ target_cls, const float* __restrict__ scalers,
    float* __restrict__ out) {
  int lane = threadIdx.x & 63;
  int wid  = threadIdx.x >> 6;
  __shared__ float semb_s[4][E_N];              // per-wave slice: no barrier needed
  unsigned wg = blockIdx.x * 4u + (unsigned)wid;

  for (unsigned row = wg; row < (unsigned)NROWS; row += GOUT*4u) {
    int b = row >= (unsigned)A_TOT;
    int a = (int)row - b*A_TOT;

    // assignment: lane l holds candidates t=l and t=l+64
    const float* trow = tmatT + (size_t)row * T_N;
    float v1 = 0.f; int t1 = 0x7fff;
    {
      float va = (lane < T_N) ? trow[lane] : 0.f;
      if (lane < T_N && va > 0.f && va >= kth[b*T_N + lane]) { v1 = va; t1 = lane; }
      int l2 = lane + 64;
      if (l2 < T_N) {
        float vb = trow[l2];
        if (vb > 0.f && vb >= kth[b*T_N + l2]) {
          if (vb > v1) { v1 = vb; t1 = l2; }   // tie keeps smaller t
        }
      }
    }
    #pragma unroll
    for (int off = 32; off; off >>= 1) {
      float ov = __shfl_xor(v1, off); int ot = __shfl_xor(t1, off);
      if (ov > v1 || (ov == v1 && ot < t1)) { v1 = ov; t1 = ot; }
    }
    int  anyv = v1 > 0.f;
    int  u    = anyv ? t1 : 0;
    int  bu   = b*T_N + u;
    float4 tb = *(const float4*)(target_bbox + bu*4);
    float ng  = anyv ? v1 / (maxt[bu] + EPSF) * maxiou[bu] : 0.f;
    float vld = anyv ? 1.f : 0.f;
    float s   = scalers[a];
    float area = (tb.z - tb.x)*(tb.w - tb.y)/(640.f*640.f);
    int  ct   = target_cls[bu];
    bool valid = anyv != 0;
    size_t base = (size_t)row * ROW_N;

    if (lane < E_N) semb_s[wid][lane] = mask_embs[(size_t)row*E_N + lane];

    {
      unsigned p = (unsigned)lane;               // 0..63
      float val = (p < 4u) ? pred_boxes[(size_t)row*4 + p] / s
                           : cls_logits[(size_t)row*C_N + (p-4u)];
      out[base + p] = val;
    }
    if (lane < 28) {
      unsigned p = 64u + (unsigned)lane;         // 64..91
      if (p < 84u)       out[base + p] = cls_logits[(size_t)row*C_N + (p-4u)];
      else if (p < 88u) {
        float t = (p==84u)?tb.x:((p==85u)?tb.y:((p==86u)?tb.z:tb.w));
        out[base + p] = t / s;
      }
      else if (p == 88u) out[base + 88] = vld;
      else if (p == 89u) { if (valid) out[base + 89 + ct] = ng; }
      else if (p == 90u) out[base + 4265] = area;
      else               out[base + 4266] = vld;
    }

    if (valid) {
      float x1s=tb.x*0.1f, y1s=tb.y*0.1f, x2s=tb.z*0.1f, y2s=tb.w*0.1f;
      int hlo = max(0, (int)ceilf(y1s)), hhi = min(MH_N, (int)ceilf(y2s));
      int wlo = max(0, (int)ceilf(x1s)), whi = min(MW_N, (int)ceilf(x2s));
      int nw = whi - wlo, nh = hhi - hlo;
      int ncell = (nw > 0 && nh > 0) ? nw * nh : 0;
      const float* tmrow = tmaskT + (size_t)(b*T_N + u) * (MH_N*MW_N);
      for (int i = lane; i < ncell; i += 64) {
        int h = hlo + i / nw, w = wlo + i % nw;
        const float* pr = protos + ((size_t)((b*MH_N + h)*MW_N + w)) * E_N;
        float acc = 0.f;
        #pragma unroll
        for (int e = 0; e < E_N; e++) acc += semb_s[wid][e] * pr[e];
        int p = (h << 6) | w;
        out[base + 169  + p] = 1.f / (1.f + expf(-acc));
        out[base + 4267 + p] = tmrow[p];
      }
    }
  }
}

extern "C" void kernel_launch(void* const* d_in, const int* in_sizes, int n_in,
                              void* d_out, int out_size, void* d_ws, size_t ws_size,
                              hipStream_t stream) {
  const float* cls_logits   = (const float*)d_in[0];
  const float* pred_boxes   = (const float*)d_in[1];
  const float* mask_embs    = (const float*)d_in[2];
  const float* protos       = (const float*)d_in[3];
  const int*   target_cls   = (const int*)  d_in[4];
  const float* target_bbox  = (const float*)d_in[5];
  const float* target_masks = (const float*)d_in[6];
  const float* anchors      = (const float*)d_in[7];
  const float* scalers      = (const float*)d_in[8];
  float* out = (float*)d_out;

  // ws layout (floats); ~10 MB total
  float* ws     = (float*)d_ws;
  float* tmatT  = ws;                                  // 1,680,000  [row][t]
  float* tmaskT = tmatT + (size_t)NROWS*T_N;           // 819,200    [b][t][h][w]
  float* kth    = tmaskT + (size_t)B_N*T_N*MH_N*MW_N;  // 200
  float* maxt   = kth + B_N*T_N;                       // 200
  float* maxiou = maxt + B_N*T_N;                      // 200

  hipMemsetAsync(out, 0, (size_t)out_size * sizeof(float), stream);
  k_prep<<<PREP_B, 512, 0, stream>>>(cls_logits, pred_boxes, target_bbox,
                                     target_cls, anchors, target_masks,
                                     tmatT, tmaskT, kth, maxt, maxiou);
  k_out<<<GOUT, 256, 0, stream>>>(cls_logits, pred_boxes, mask_embs, protos,
                                  tmaskT, tmatT, kth, maxt, maxiou,
                                  target_bbox, target_cls, scalers, out);
}